// Round 15
// baseline (236.441 us; speedup 1.0000x reference)
//
#include <hip/hip_runtime.h>

#define DECAY 0.25f

typedef float fx4 __attribute__((ext_vector_type(4)));

__device__ __forceinline__ fx4 step4(fx4 mem, fx4 spk, fx4 xi, fx4* s_out)
{
    fx4 m = (mem - spk * 0.5f) * DECAY + xi;
    fx4 s;
    s.x = rintf(fminf(fmaxf(m.x, 0.f), 1.f));
    s.y = rintf(fminf(fmaxf(m.y, 0.f), 1.f));
    s.z = rintf(fminf(fmaxf(m.z, 0.f), 1.f));
    s.w = rintf(fminf(fmaxf(m.w, 0.f), 1.f));
    *s_out = s;
    return m;
}

// Wave-per-plane: each wave has exactly 1 read stream + 1 write stream
// (copy-shaped traffic), recurrence coupling resolved through LDS.
__global__ __launch_bounds__(256) void lif_mem_update_kernel(
    const float* __restrict__ x, float* __restrict__ out, long long n4)
{
    __shared__ fx4 lds[4][256];          // [plane][position], 16 KiB

    const int tid  = threadIdx.x;
    const int lane = tid & 63;
    const int w    = tid >> 6;           // wave id == plane id (4 waves)
    const long long chunk = (long long)blockIdx.x * 256;
    if (chunk >= n4) return;

    const fx4* __restrict__ x4 = (const fx4*)x;
    fx4* __restrict__ o4 = (fx4*)out;

    // Phase R: wave w stages plane w's 4-KB chunk (4 contiguous 1-KB runs).
    const fx4* __restrict__ src = x4 + (long long)w * n4 + chunk;
    #pragma unroll
    for (int j = 0; j < 4; ++j)
        lds[w][j * 64 + lane] = src[j * 64 + lane];

    __syncthreads();

    // Phase C: lane (w,l) runs the recurrence for position p = w*64+l.
    // Slots lds[0..3][p] are read and then overwritten only by this lane.
    {
        const int p = tid;               // w*64 + lane
        fx4 x0 = lds[0][p], x1 = lds[1][p], x2 = lds[2][p], x3 = lds[3][p];
        fx4 zero = (fx4)(0.f);
        fx4 s0, s1, s2, s3;
        fx4 m;
        m = step4(zero, zero, x0, &s0);
        m = step4(m,    s0,   x1, &s1);
        m = step4(m,    s1,   x2, &s2);
        m = step4(m,    s2,   x3, &s3);
        lds[0][p] = s0; lds[1][p] = s1; lds[2][p] = s2; lds[3][p] = s3;
    }

    __syncthreads();

    // Phase W: wave w streams output plane w's 4-KB chunk (1 write stream).
    fx4* __restrict__ dst = o4 + (long long)w * n4 + chunk;
    #pragma unroll
    for (int j = 0; j < 4; ++j)
        dst[j * 64 + lane] = lds[w][j * 64 + lane];
}

extern "C" void kernel_launch(void* const* d_in, const int* in_sizes, int n_in,
                              void* d_out, int out_size, void* d_ws, size_t ws_size,
                              hipStream_t stream)
{
    const float* x = (const float*)d_in[0];
    float* out = (float*)d_out;

    long long total = (long long)in_sizes[0];   // 33554432 floats = [4][8388608]
    long long nplane = total / 4;               // 8388608 floats per plane
    long long n4 = nplane / 4;                  // 2097152 fx4 per plane

    const int block = 256;                      // 4 waves = 4 planes
    long long grid = (n4 + 255) / 256;          // 8192 blocks, 256 fx4/plane each
    lif_mem_update_kernel<<<(int)grid, block, 0, stream>>>(x, out, n4);
}